// Round 1
// baseline (373.127 us; speedup 1.0000x reference)
//
#include <hip/hip_runtime.h>

#define CC 8
#define KK 64
#define BB 8192

// ---------------- workspace layout (bytes) ----------------
// Regions that must be zeroed each launch come first (one memset covers them).
#define OFF_G       0                         // double G[C][K][K]   = 262144
#define OFF_GSUM    262144                    // float  gsum[C][K]   =   2048
#define OFF_GCOUNT  264192                    // int    gcount[C]    =     32
#define OFF_GFIRST  264224                    // int    gfirst[C]    =     32  (init 0x7f)
#define OFF_S1      264256                    // double S1[C][K][K]  = 262144
#define OFF_INV     526400                    // double invS2[K][K]  =  32768
#define OFF_LOG     559168                    // double logdets[9]   =     72
#define WS_NEEDED   559240

// ---------------- pass 1: per-class sums / counts / first positions ----------------
__global__ __launch_bounds__(256) void stats_kernel(
    const float* __restrict__ mu, const int* __restrict__ labels,
    float* __restrict__ gsum, int* __restrict__ gcount, int* __restrict__ gfirst) {
  __shared__ float lsum[CC * KK];
  __shared__ int lcount[CC];
  __shared__ int lfirst[CC];
  int tid = threadIdx.x;
  for (int i = tid; i < CC * KK; i += 256) lsum[i] = 0.f;
  if (tid < CC) { lcount[tid] = 0; lfirst[tid] = BB; }
  __syncthreads();
  int k = tid & 63;
  int rsub = tid >> 6;  // 0..3
  for (int row = blockIdx.x * 4 + rsub; row < BB; row += gridDim.x * 4) {
    int lab = labels[row];
    atomicAdd(&lsum[lab * KK + k], mu[row * KK + k]);
    if (k == 0) {
      atomicAdd(&lcount[lab], 1);
      atomicMin(&lfirst[lab], row);
    }
  }
  __syncthreads();
  for (int i = tid; i < CC * KK; i += 256) atomicAdd(&gsum[i], lsum[i]);
  if (tid < CC) {
    atomicAdd(&gcount[tid], lcount[tid]);
    atomicMin(&gfirst[tid], lfirst[tid]);
  }
}

// ---------------- pass 2: per-class Gram matrices G_c = sum_{label==c} x x^T ----------------
__global__ __launch_bounds__(256) void gram_kernel(
    const float* __restrict__ mu, const int* __restrict__ labels,
    double* __restrict__ G) {
  int c = blockIdx.y;
  int chunk = blockIdx.x;          // 32 chunks of 256 rows
  int tid = threadIdx.x;
  int tx = tid & 15, ty = tid >> 4;
  __shared__ float rows[16][KK];
  __shared__ int labs[16];
  double acc[4][4];
#pragma unroll
  for (int a = 0; a < 4; ++a)
#pragma unroll
    for (int b = 0; b < 4; ++b) acc[a][b] = 0.0;
  int base = chunk * 256;
  for (int r0 = 0; r0 < 256; r0 += 16) {
    __syncthreads();
#pragma unroll
    for (int i = 0; i < 4; ++i) {
      int idx = tid + i * 256;
      rows[idx >> 6][idx & 63] = mu[(size_t)(base + r0) * KK + idx];
    }
    if (tid < 16) labs[tid] = labels[base + r0 + tid];
    __syncthreads();
    for (int r = 0; r < 16; ++r) {
      if (labs[r] != c) continue;          // block-uniform branch: cheap skip
      const float* rw = rows[r];
      float ai[4], bj[4];
#pragma unroll
      for (int a = 0; a < 4; ++a) ai[a] = rw[ty * 4 + a];
#pragma unroll
      for (int b = 0; b < 4; ++b) bj[b] = rw[tx * 4 + b];
#pragma unroll
      for (int a = 0; a < 4; ++a)
#pragma unroll
        for (int b = 0; b < 4; ++b) acc[a][b] += (double)ai[a] * (double)bj[b];
    }
  }
  double* Gc = G + (size_t)c * KK * KK;
#pragma unroll
  for (int a = 0; a < 4; ++a)
#pragma unroll
    for (int b = 0; b < 4; ++b)
      atomicAdd(&Gc[(ty * 4 + a) * KK + tx * 4 + b], acc[a][b]);
}

// ---------------- pass 3: build Sigma's, Cholesky, logdets, inv(Sigma_total) ----------------
// blocks 0..7: class c -> S1[c], logdets[c]
// block 8: Sigma_total  -> logdets[8], invS2
__global__ __launch_bounds__(64) void factor_kernel(
    const double* __restrict__ G, const float* __restrict__ cov,
    const float* __restrict__ gsum, const int* __restrict__ gcount,
    double* __restrict__ S1, double* __restrict__ invS2,
    double* __restrict__ logdets) {
  int blk = blockIdx.x;
  int t = threadIdx.x;  // 0..63, one wave
  __shared__ double a[KK][KK + 1];
  __shared__ double vec[KK];

  if (blk < CC) {
    int c = blk;
    int nc = gcount[c];
    double safe = nc > 0 ? (double)nc : 1.0;
    vec[t] = (double)gsum[c * KK + t] / safe;
    __syncthreads();
    const double* Gc = G + (size_t)c * KK * KK;
    double* S1c = S1 + (size_t)c * KK * KK;
    double vt = vec[t];
    for (int j = 0; j < KK; ++j) {
      double v = (double)cov[t * KK + j] + (Gc[t * KK + j] - (double)nc * vt * vec[j]) / safe;
      a[t][j] = v;
      S1c[t * KK + j] = v;
    }
  } else {
    double s = 0.0;
    for (int c = 0; c < CC; ++c) s += (double)gsum[c * KK + t];
    vec[t] = s / (double)BB;
    __syncthreads();
    double vt = vec[t];
    for (int j = 0; j < KK; ++j) {
      double g = 0.0;
      for (int c = 0; c < CC; ++c) g += G[(size_t)c * KK * KK + t * KK + j];
      a[t][j] = (double)cov[t * KK + j] + g * (1.0 / (double)BB) - vt * vec[j];
    }
  }
  __syncthreads();

  // Cholesky (lower, in place), row t owned by thread t
  for (int k = 0; k < KK; ++k) {
    if (t == k) a[k][k] = sqrt(a[k][k]);
    __syncthreads();
    if (t > k) a[t][k] /= a[k][k];
    __syncthreads();
    if (t > k) {
      double lik = a[t][k];
      for (int j = k + 1; j <= t; ++j) a[t][j] -= lik * a[j][k];
    }
  }
  __syncthreads();

  double ld = log(a[t][t]);
#pragma unroll
  for (int off = 32; off; off >>= 1) ld += __shfl_down(ld, off);
  if (t == 0) logdets[blk] = 2.0 * ld;

  if (blk == CC) {
    // Linv column t, stored transposed in the (unused) strict upper triangle:
    //   X[i][t] (i>t) -> a[t][i];  X[t][t] -> vec[t]
    vec[t] = 1.0 / a[t][t];
    for (int i = t + 1; i < KK; ++i) {
      double s = a[i][t] * vec[t];
      for (int j = t + 1; j < i; ++j) s += a[i][j] * a[t][j];
      a[t][i] = -s / a[i][i];
    }
    __syncthreads();
    // invS2 = Linv^T Linv ; invS2[t][j] = sum_{k>=max(t,j)} X[k][t] X[k][j]
    for (int j = 0; j < KK; ++j) {
      int k0 = t > j ? t : j;
      double s = 0.0;
      for (int k2 = k0; k2 < KK; ++k2) {
        double xkt = (k2 == t) ? vec[t] : a[t][k2];
        double xkj = (k2 == j) ? vec[j] : a[j][k2];
        s += xkt * xkj;
      }
      invS2[t * KK + j] = s;
    }
  }
}

// ---------------- pass 4: KL per class + weighted combine ----------------
__global__ __launch_bounds__(64) void combine_kernel(
    const double* __restrict__ S1, const double* __restrict__ invS2,
    const double* __restrict__ logdets, const int* __restrict__ gcount,
    const int* __restrict__ gfirst, const float* __restrict__ gsum,
    float* __restrict__ out) {
  int t = threadIdx.x;  // 0..63
  __shared__ double mu_total[KK];
  __shared__ double d[KK];
  __shared__ int lastkey;
  if (t == 0) {
    int best = 0;
    long long bestv = -2;
    for (int c = 0; c < CC; ++c) {
      long long v = gcount[c] > 0 ? (long long)gfirst[c] : -1;
      if (v > bestv) { bestv = v; best = c; }   // strict > == argmax first-index tie-break
    }
    lastkey = best;
  }
  {
    double s = 0.0;
    for (int c = 0; c < CC; ++c) s += (double)gsum[c * KK + t];
    mu_total[t] = s / (double)BB;
  }
  __syncthreads();

  double total = 0.0;
  for (int c = 0; c < CC; ++c) {
    int nc = gcount[c];
    double safe = nc > 0 ? (double)nc : 1.0;
    d[t] = mu_total[t] - (double)gsum[c * KK + t] / safe;
    __syncthreads();
    const double* S1c = S1 + (size_t)c * KK * KK;
    double tr = 0.0, q = 0.0;
    for (int j = 0; j < KK; ++j) {
      double w = invS2[t * KK + j];
      tr += w * S1c[t * KK + j];
      q += w * d[j];
    }
    q *= d[t];
#pragma unroll
    for (int off = 32; off; off >>= 1) {
      tr += __shfl_down(tr, off);
      q += __shfl_down(q, off);
    }
    if (t == 0) {
      double kl = 0.5 * (tr + q - (double)KK + logdets[CC] - logdets[c]);
      double w = (nc > 0 && c != lastkey) ? (double)nc : 0.0;
      total += kl * w;
    }
    __syncthreads();  // before d[] is overwritten for next class
  }
  if (t == 0) out[0] = (float)(total / (double)BB);
}

extern "C" void kernel_launch(void* const* d_in, const int* in_sizes, int n_in,
                              void* d_out, int out_size, void* d_ws, size_t ws_size,
                              hipStream_t stream) {
  (void)in_sizes; (void)n_in; (void)out_size; (void)ws_size;
  const float* mu = (const float*)d_in[0];
  const int* labels = (const int*)d_in[1];
  const float* cov = (const float*)d_in[2];
  float* out = (float*)d_out;
  char* ws = (char*)d_ws;

  double* G = (double*)(ws + OFF_G);
  float* gsum = (float*)(ws + OFF_GSUM);
  int* gcount = (int*)(ws + OFF_GCOUNT);
  int* gfirst = (int*)(ws + OFF_GFIRST);
  double* S1 = (double*)(ws + OFF_S1);
  double* invS2 = (double*)(ws + OFF_INV);
  double* logdets = (double*)(ws + OFF_LOG);

  // zero accumulators (G, gsum, gcount); gfirst -> 0x7f7f7f7f (> B, acts as +inf for atomicMin)
  hipMemsetAsync(ws, 0, OFF_GFIRST, stream);
  hipMemsetAsync(ws + OFF_GFIRST, 0x7f, CC * sizeof(int), stream);

  stats_kernel<<<256, 256, 0, stream>>>(mu, labels, gsum, gcount, gfirst);
  gram_kernel<<<dim3(32, CC), 256, 0, stream>>>(mu, labels, G);
  factor_kernel<<<CC + 1, 64, 0, stream>>>(G, cov, gsum, gcount, S1, invS2, logdets);
  combine_kernel<<<1, 64, 0, stream>>>(S1, invS2, logdets, gcount, gfirst, gsum, out);
}

// Round 2
// 196.118 us; speedup vs baseline: 1.9026x; 1.9026x over previous
//
#include <hip/hip_runtime.h>

#define CC 8
#define KK 64
#define BB 8192

// ---------------- workspace layout (bytes) ----------------
// Regions that must be zeroed each launch come first (one memset covers them).
#define OFF_G       0                         // double G[C][K][K]   = 262144
#define OFF_GSUM    262144                    // float  gsum[C][K]   =   2048
#define OFF_GCOUNT  264192                    // int    gcount[C]    =     32
#define OFF_GFIRST  264224                    // int    gfirst[C]    =     32  (init 0x7f)
#define OFF_INV     264256                    // double invS2[K][K]  =  32768
#define OFF_LOG     297024                    // double logdets[9]   =     72

// ---------------- pass 1: per-class sums / counts / first positions ----------------
__global__ __launch_bounds__(256) void stats_kernel(
    const float* __restrict__ mu, const int* __restrict__ labels,
    float* __restrict__ gsum, int* __restrict__ gcount, int* __restrict__ gfirst) {
  __shared__ float lsum[CC * KK];
  __shared__ int lcount[CC];
  __shared__ int lfirst[CC];
  int tid = threadIdx.x;
  for (int i = tid; i < CC * KK; i += 256) lsum[i] = 0.f;
  if (tid < CC) { lcount[tid] = 0; lfirst[tid] = BB; }
  __syncthreads();
  int k = tid & 63;
  int rsub = tid >> 6;  // 0..3
  for (int row = blockIdx.x * 4 + rsub; row < BB; row += gridDim.x * 4) {
    int lab = labels[row];
    atomicAdd(&lsum[lab * KK + k], mu[row * KK + k]);
    if (k == 0) {
      atomicAdd(&lcount[lab], 1);
      atomicMin(&lfirst[lab], row);
    }
  }
  __syncthreads();
  for (int i = tid; i < CC * KK; i += 256) atomicAdd(&gsum[i], lsum[i]);
  if (tid < CC) {
    atomicAdd(&gcount[tid], lcount[tid]);
    atomicMin(&gfirst[tid], lfirst[tid]);
  }
}

// ---------------- pass 2: per-class Gram matrices G_c = sum_{label==c} x x^T ----------------
__global__ __launch_bounds__(256) void gram_kernel(
    const float* __restrict__ mu, const int* __restrict__ labels,
    double* __restrict__ G) {
  int c = blockIdx.y;
  int chunk = blockIdx.x;          // 32 chunks of 256 rows
  int tid = threadIdx.x;
  int tx = tid & 15, ty = tid >> 4;
  __shared__ float rows[16][KK];
  __shared__ int labs[16];
  double acc[4][4];
#pragma unroll
  for (int a = 0; a < 4; ++a)
#pragma unroll
    for (int b = 0; b < 4; ++b) acc[a][b] = 0.0;
  int base = chunk * 256;
  for (int r0 = 0; r0 < 256; r0 += 16) {
    __syncthreads();
#pragma unroll
    for (int i = 0; i < 4; ++i) {
      int idx = tid + i * 256;
      rows[idx >> 6][idx & 63] = mu[(size_t)(base + r0) * KK + idx];
    }
    if (tid < 16) labs[tid] = labels[base + r0 + tid];
    __syncthreads();
    for (int r = 0; r < 16; ++r) {
      if (labs[r] != c) continue;          // block-uniform branch: cheap skip
      const float* rw = rows[r];
      float ai[4], bj[4];
#pragma unroll
      for (int a = 0; a < 4; ++a) ai[a] = rw[ty * 4 + a];
#pragma unroll
      for (int b = 0; b < 4; ++b) bj[b] = rw[tx * 4 + b];
#pragma unroll
      for (int a = 0; a < 4; ++a)
#pragma unroll
        for (int b = 0; b < 4; ++b) acc[a][b] += (double)ai[a] * (double)bj[b];
    }
  }
  double* Gc = G + (size_t)c * KK * KK;
#pragma unroll
  for (int a = 0; a < 4; ++a)
#pragma unroll
    for (int b = 0; b < 4; ++b)
      atomicAdd(&Gc[(ty * 4 + a) * KK + tx * 4 + b], acc[a][b]);
}

// ---------------- pass 3: Cholesky (rows in registers, shfl cross-lane), logdets, inv(Sigma_total) ----------------
// blocks 0..7: class c -> logdets[c]
// block 8: Sigma_total -> logdets[8], invS2
__global__ __launch_bounds__(64, 1) void factor_kernel(
    const double* __restrict__ G, const float* __restrict__ cov,
    const float* __restrict__ gsum, const int* __restrict__ gcount,
    double* __restrict__ invS2, double* __restrict__ logdets) {
  int blk = blockIdx.x;
  int t = threadIdx.x;  // 0..63, one wave (wave-synchronous block)
  __shared__ double vec[KK];
  __shared__ double La[KK * KK];  // L column-major: La[j*KK+i] = L[i][j]
  __shared__ double Xl[KK * KK];  // X columns:      Xl[k*KK+j] = X[k][j]
  __shared__ double Ldi[KK];      // 1/L[i][i]

  double r[KK];  // this lane's row t of Sigma (statically indexed only)

  // ---- build Sigma row t in registers (all global reads coalesced: fixed j, lanes t consecutive;
  //      row t == column t by symmetry of cov and G) ----
  if (blk < CC) {
    int nc = gcount[blk];
    double safe = nc > 0 ? (double)nc : 1.0;
    vec[t] = (double)gsum[blk * KK + t] / safe;
    __syncthreads();
    double mt = vec[t];
    double ncd = (double)nc;
    const double* Gc = G + (size_t)blk * KK * KK;
#pragma unroll
    for (int j = 0; j < KK; ++j)
      r[j] = (double)cov[j * KK + t] + (Gc[j * KK + t] - ncd * vec[j] * mt) / safe;
  } else {
    double s = 0.0;
#pragma unroll
    for (int c = 0; c < CC; ++c) s += (double)gsum[c * KK + t];
    vec[t] = s / (double)BB;
    __syncthreads();
    double mt = vec[t];
#pragma unroll
    for (int j = 0; j < KK; ++j) {
      double g = 0.0;
#pragma unroll
      for (int c = 0; c < CC; ++c) g += G[(size_t)c * KK * KK + j * KK + t];
      r[j] = (double)cov[j * KK + t] + g * (1.0 / (double)BB) - vec[j] * mt;
    }
  }

  // ---- register Cholesky: no LDS in the hot loop, no barriers, cross-lane via shfl ----
  double myd = 1.0;  // L[t][t] for this lane
#pragma unroll
  for (int k = 0; k < KK; ++k) {
    double Lkk = sqrt(__shfl(r[k], k));
    double inv = 1.0 / Lkk;
    if (t == k) { r[k] = Lkk; myd = Lkk; }
    else if (t > k) r[k] *= inv;
    double rk = r[k];  // L[t][k] for t>=k; garbage (predicated off) for t<k
#pragma unroll
    for (int j = k + 1; j < KK; ++j) {
      double Ljk = __shfl(r[k], j);  // element L[j][k], same for all lanes
      if (j <= t) r[j] -= rk * Ljk;
    }
  }

  // ---- logdet = 2*sum(log(diag)) ----
  double ld = log(myd);
#pragma unroll
  for (int m = 32; m; m >>= 1) ld += __shfl_xor(ld, m);
  if (t == 0) logdets[blk] = 2.0 * ld;

  // ---- block 8 only: invS2 = (L L^T)^{-1} via column-parallel triangular solve ----
  if (blk == CC) {
    // store L column-major (lane t writes row t at consecutive addresses per j: conflict-free)
#pragma unroll
    for (int j = 0; j < KK; ++j) La[j * KK + t] = r[j];
    Ldi[t] = 1.0 / myd;
    __syncthreads();

    // lane t solves L x = e_t; x[i] = 0 for i<t falls out naturally (s==0)
    double x[KK];
#pragma unroll
    for (int i = 0; i < KK; ++i) {
      double s = (i == t) ? 1.0 : 0.0;
#pragma unroll
      for (int j = 0; j < i; ++j) s -= La[j * KK + i] * x[j];  // uniform addr -> broadcast
      x[i] = s * Ldi[i];
    }

    // publish X columns (lane-consecutive writes: conflict-free)
#pragma unroll
    for (int k = 0; k < KK; ++k) Xl[k * KK + t] = x[k];
    __syncthreads();

    // invS2[t][j] = sum_k X[k][t] X[k][j]; x[k]=0 for k<t handles the lower bound
#pragma unroll
    for (int j = 0; j < KK; ++j) {
      double s = 0.0;
#pragma unroll
      for (int k = j; k < KK; ++k) s += x[k] * Xl[k * KK + j];  // uniform addr -> broadcast
      invS2[j * KK + t] = s;  // coalesced; symmetric matrix
    }
  }
}

// ---------------- pass 4: KL per class + weighted combine ----------------
// tr(inv*S1c) = tr(inv*cov) + (tr(inv*Gc) - nc * m^T inv m)/safe  -- no S1 materialization
__global__ __launch_bounds__(64) void combine_kernel(
    const double* __restrict__ G, const double* __restrict__ invS2,
    const double* __restrict__ logdets, const float* __restrict__ cov,
    const int* __restrict__ gcount, const int* __restrict__ gfirst,
    const float* __restrict__ gsum, float* __restrict__ out) {
  int t = threadIdx.x;  // 0..63
  __shared__ double invl[KK * KK];
  __shared__ double mu_total[KK];
  __shared__ double mv[KK];
  __shared__ double dv[KK];
  __shared__ double tic_s;
  __shared__ int lastkey;

  if (t == 0) {
    int best = 0;
    long long bestv = -2;
    for (int c = 0; c < CC; ++c) {
      long long v = gcount[c] > 0 ? (long long)gfirst[c] : -1;
      if (v > bestv) { bestv = v; best = c; }  // strict > == argmax first-index tie-break
    }
    lastkey = best;
  }

  // stage invS2 (coalesced) + tr(inv*cov) partial
  double tic = 0.0;
#pragma unroll
  for (int m = 0; m < KK; ++m) {
    double w = invS2[m * KK + t];
    invl[m * KK + t] = w;
    tic += w * (double)cov[m * KK + t];
  }
  {
    double s = 0.0;
#pragma unroll
    for (int c = 0; c < CC; ++c) s += (double)gsum[c * KK + t];
    mu_total[t] = s / (double)BB;
  }
#pragma unroll
  for (int m = 32; m; m >>= 1) tic += __shfl_xor(tic, m);
  if (t == 0) tic_s = tic;
  __syncthreads();

  double total = 0.0;
  for (int c = 0; c < CC; ++c) {
    int nc = gcount[c];
    double safe = nc > 0 ? (double)nc : 1.0;
    const double* Gc = G + (size_t)c * KK * KK;
    double mt = (double)gsum[c * KK + t] / safe;
    mv[t] = mt;
    double dt = mu_total[t] - mt;
    dv[t] = dt;
    __syncthreads();
    double tg = 0.0, qm = 0.0, qd = 0.0;
#pragma unroll
    for (int m = 0; m < KK; ++m) {
      double w = invl[m * KK + t];  // lane-consecutive: conflict-free
      tg += w * Gc[m * KK + t];     // coalesced global
      qm += w * mv[m];              // broadcast
      qd += w * dv[m];              // broadcast
    }
    qm *= mt;
    qd *= dt;
#pragma unroll
    for (int m = 32; m; m >>= 1) {
      tg += __shfl_down(tg, m);
      qm += __shfl_down(qm, m);
      qd += __shfl_down(qd, m);
    }
    if (t == 0) {
      double tr = tic_s + (tg - (double)nc * qm) / safe;
      double kl = 0.5 * (tr + qd - (double)KK + logdets[CC] - logdets[c]);
      double w = (nc > 0 && c != lastkey) ? (double)nc : 0.0;
      total += kl * w;
    }
    __syncthreads();  // before mv/dv overwritten next class
  }
  if (t == 0) out[0] = (float)(total / (double)BB);
}

extern "C" void kernel_launch(void* const* d_in, const int* in_sizes, int n_in,
                              void* d_out, int out_size, void* d_ws, size_t ws_size,
                              hipStream_t stream) {
  (void)in_sizes; (void)n_in; (void)out_size; (void)ws_size;
  const float* mu = (const float*)d_in[0];
  const int* labels = (const int*)d_in[1];
  const float* cov = (const float*)d_in[2];
  float* out = (float*)d_out;
  char* ws = (char*)d_ws;

  double* G = (double*)(ws + OFF_G);
  float* gsum = (float*)(ws + OFF_GSUM);
  int* gcount = (int*)(ws + OFF_GCOUNT);
  int* gfirst = (int*)(ws + OFF_GFIRST);
  double* invS2 = (double*)(ws + OFF_INV);
  double* logdets = (double*)(ws + OFF_LOG);

  // zero accumulators (G, gsum, gcount); gfirst -> 0x7f7f7f7f (> B, acts as +inf for atomicMin)
  hipMemsetAsync(ws, 0, OFF_GFIRST, stream);
  hipMemsetAsync(ws + OFF_GFIRST, 0x7f, CC * sizeof(int), stream);

  stats_kernel<<<256, 256, 0, stream>>>(mu, labels, gsum, gcount, gfirst);
  gram_kernel<<<dim3(32, CC), 256, 0, stream>>>(mu, labels, G);
  factor_kernel<<<CC + 1, 64, 0, stream>>>(G, cov, gsum, gcount, invS2, logdets);
  combine_kernel<<<1, 64, 0, stream>>>(G, invS2, logdets, cov, gcount, gfirst, gsum, out);
}

// Round 3
// 178.174 us; speedup vs baseline: 2.0942x; 1.1007x over previous
//
#include <hip/hip_runtime.h>

#define CC 8
#define KK 64
#define BB 8192

// ---------------- workspace layout (bytes) ----------------
#define OFF_G       0                         // double G[C][K][K]   = 262144
#define OFF_GSUM    262144                    // float  gsum[C][K]   =   2048
#define OFF_GCOUNT  264192                    // int    gcount[C]    =     32
#define OFF_GFIRST  264224                    // int    gfirst[C]    =     32  (init 0x7f)
#define OFF_INV     264256                    // double invS2[K][K]  =  32768
#define OFF_LOG     297024                    // double logdets[9]   =     72

// ---------------- pass 1: per-class Gram matrices + fused stats ----------------
__global__ __launch_bounds__(256) void gram_stats_kernel(
    const float* __restrict__ mu, const int* __restrict__ labels,
    double* __restrict__ G, float* __restrict__ gsum,
    int* __restrict__ gcount, int* __restrict__ gfirst) {
  int c = blockIdx.y;
  int chunk = blockIdx.x;          // 32 chunks of 256 rows
  int tid = threadIdx.x;
  int tx = tid & 15, ty = tid >> 4;
  __shared__ float rows[16][KK];
  __shared__ int labs[16];
  double acc[4][4];
#pragma unroll
  for (int a = 0; a < 4; ++a)
#pragma unroll
    for (int b = 0; b < 4; ++b) acc[a][b] = 0.0;
  float rsum = 0.f;                // stats: per-column class sum (tid<64)
  int cnt = 0, first = BB;         // stats: tid==0
  int base = chunk * 256;
  for (int r0 = 0; r0 < 256; r0 += 16) {
    __syncthreads();
#pragma unroll
    for (int i = 0; i < 4; ++i) {
      int idx = tid + i * 256;
      rows[idx >> 6][idx & 63] = mu[(size_t)(base + r0) * KK + idx];
    }
    if (tid < 16) labs[tid] = labels[base + r0 + tid];
    __syncthreads();
    if (tid < 64) {
#pragma unroll 4
      for (int r = 0; r < 16; ++r)
        if (labs[r] == c) rsum += rows[r][tid];
    }
    if (tid == 0) {
      for (int r = 0; r < 16; ++r)
        if (labs[r] == c) { cnt++; first = min(first, base + r0 + r); }
    }
    for (int r = 0; r < 16; ++r) {
      if (labs[r] != c) continue;          // block-uniform branch: cheap skip
      const float* rw = rows[r];
      float ai[4], bj[4];
#pragma unroll
      for (int a = 0; a < 4; ++a) ai[a] = rw[ty * 4 + a];
#pragma unroll
      for (int b = 0; b < 4; ++b) bj[b] = rw[tx * 4 + b];
#pragma unroll
      for (int a = 0; a < 4; ++a)
#pragma unroll
        for (int b = 0; b < 4; ++b) acc[a][b] += (double)ai[a] * (double)bj[b];
    }
  }
  double* Gc = G + (size_t)c * KK * KK;
#pragma unroll
  for (int a = 0; a < 4; ++a)
#pragma unroll
    for (int b = 0; b < 4; ++b)
      atomicAdd(&Gc[(ty * 4 + a) * KK + tx * 4 + b], acc[a][b]);
  if (tid < 64) atomicAdd(&gsum[c * KK + tid], rsum);
  if (tid == 0 && cnt) {
    atomicAdd(&gcount[c], cnt);
    atomicMin(&gfirst[c], first);
  }
}

// ---------------- pass 2: blocked Cholesky (panel=8), logdets, inv(Sigma_total) ----------------
// 9 blocks x 64 threads (1 wave, wave-synchronous: no barriers).
// Lane t owns row t. Cross-lane via shfl + broadcast LDS (in-order LDS pipe).
// Trailing updates ping-pong bufA<->bufB so reads never alias pending writes -> pipelined.
__global__ __launch_bounds__(64) void factor_kernel(
    const double* __restrict__ G, const float* __restrict__ cov,
    const float* __restrict__ gsum, const int* __restrict__ gcount,
    double* __restrict__ invS2, double* __restrict__ logdets,
    float* __restrict__ out) {
  int blk = blockIdx.x;
  int t = threadIdx.x;  // 0..63
  __shared__ double bufA[KK][KK + 1];
  __shared__ double bufB[KK][KK + 1];
  __shared__ double Lb[KK][KK + 1];   // normalized L (only written by blk==CC)
  __shared__ double panelb[8][KK];    // current panel columns (unnormalized)
  __shared__ double Ldi[KK];          // 1/L[k][k]
  __shared__ double mb[KK];           // mean vector

  bool isS2 = (blk == CC);
  if (isS2 && t == 0) out[0] = 0.f;   // zero the output accumulator for combine

  // ---- mean ----
  double safe = 1.0, ncd = 0.0;
  if (!isS2) {
    int nc = gcount[blk];
    ncd = (double)nc;
    safe = nc > 0 ? ncd : 1.0;
    mb[t] = (double)gsum[blk * KK + t] / safe;
  } else {
    double s = 0.0;
#pragma unroll
    for (int c = 0; c < CC; ++c) s += (double)gsum[c * KK + t];
    mb[t] = s / (double)BB;
  }
  double mt = mb[t];

  // ---- build Sigma rows into bufA (coalesced: fixed j, lanes t consecutive; symmetric) ----
  if (!isS2) {
    const double* Gc = G + (size_t)blk * KK * KK;
    double inv_safe = 1.0 / safe;
#pragma unroll 8
    for (int j = 0; j < KK; ++j)
      bufA[t][j] = (double)cov[j * KK + t] + (Gc[j * KK + t] - ncd * mt * mb[j]) * inv_safe;
  } else {
    const double invB = 1.0 / (double)BB;
#pragma unroll 4
    for (int j = 0; j < KK; ++j) {
      double g = 0.0;
#pragma unroll
      for (int c = 0; c < CC; ++c) g += G[(size_t)c * KK * KK + j * KK + t];
      bufA[t][j] = (double)cov[j * KK + t] + g * invB - mt * mb[j];
    }
  }

  // ---- blocked right-looking Cholesky ----
  double (*cur)[KK + 1] = bufA;
  double (*nxt)[KK + 1] = bufB;
  double ldacc = 0.0;
#pragma unroll 1
  for (int p = 0; p < 8; ++p) {
    int P0 = p * 8;
    // Phase A: panel columns into registers
    double cc_[8];
#pragma unroll
    for (int m = 0; m < 8; ++m) cc_[m] = cur[t][P0 + m];
    // Phase B: factor panel (8 steps, registers + shfl)
    double uu[8];
    double pd = 1.0;
#pragma unroll
    for (int m = 0; m < 8; ++m) {
      double akk = __shfl(cc_[m], P0 + m);   // diagonal (uniform)
      pd *= akk;
      double inv = 1.0 / akk;
      uu[m] = cc_[m] * inv;
      panelb[m][t] = cc_[m];
      if (isS2) {
        double rsv = 1.0 / sqrt(akk);
        Lb[t][P0 + m] = cc_[m] * rsv;
        if (t == 0) Ldi[P0 + m] = rsv;
      }
#pragma unroll
      for (int mm = m + 1; mm < 8; ++mm)
        cc_[mm] -= uu[m] * __shfl(cc_[m], P0 + mm);
    }
    ldacc += log(pd);
    // Phase C: trailing update, read cur / write nxt (no alias -> pipelined)
#pragma unroll 1
    for (int j = P0 + 8; j < KK; j += 8) {
      double aj[8];
#pragma unroll
      for (int q = 0; q < 8; ++q) aj[q] = cur[t][j + q];
#pragma unroll
      for (int m = 0; m < 8; ++m)
#pragma unroll
        for (int q = 0; q < 8; ++q)
          aj[q] -= uu[m] * panelb[m][j + q];   // broadcast reads
#pragma unroll
      for (int q = 0; q < 8; ++q) nxt[t][j + q] = aj[q];
    }
    { auto tmp = cur; cur = nxt; nxt = tmp; }
  }

  if (t == 0) logdets[blk] = ldacc;   // logdet = sum log(akk) = 2 sum log L[k][k]

  // ---- blk==CC: X = L^{-1} (lane t = column t), then invS2 = X^T X ----
  if (isS2) {
    // X[i] of column t stored at bufA[i][t] (lane-consecutive: conflict-free)
#pragma unroll 1
    for (int g = 0; g < 8; ++g) {
      int I0 = g * 8;
      double sv[8], ldl[8];
#pragma unroll
      for (int m = 0; m < 8; ++m) { sv[m] = 0.0; ldl[m] = Ldi[I0 + m]; }
#pragma unroll 4
      for (int j = 0; j < I0; ++j) {
        double xj = bufA[j][t];                 // own column (lane-consecutive)
#pragma unroll
        for (int m = 0; m < 8; ++m) sv[m] += Lb[I0 + m][j] * xj;  // broadcast
      }
#pragma unroll
      for (int m = 0; m < 8; ++m) {
        int i = I0 + m;
        double x = (((i == t) ? 1.0 : 0.0) - sv[m]) * ldl[m];
#pragma unroll
        for (int mm = m + 1; mm < 8; ++mm) sv[mm] += Lb[I0 + mm][i] * x;
        bufA[i][t] = x;
      }
    }
    // invS2[r][c] = sum_{k>=r} X[k][r] * X[k][c]   (X[k][c]=0 for k<c handles other bound)
#pragma unroll 1
    for (int r = 0; r < KK; ++r) {
      double s = 0.0;
#pragma unroll 4
      for (int k = r; k < KK; ++k) s += bufA[k][r] * bufA[k][t];
      invS2[r * KK + t] = s;   // coalesced
    }
  }
}

// ---------------- pass 3: per-class KL + weighted atomic combine ----------------
// tr(inv*S1c) = tr(inv*cov) + (tr(inv*Gc) - nc * m^T inv m)/safe
__global__ __launch_bounds__(64) void combine_kernel(
    const double* __restrict__ G, const double* __restrict__ invS2,
    const double* __restrict__ logdets, const float* __restrict__ cov,
    const int* __restrict__ gcount, const int* __restrict__ gfirst,
    const float* __restrict__ gsum, float* __restrict__ out) {
  int c = blockIdx.x;   // 0..7
  int t = threadIdx.x;  // 0..63, one wave
  __shared__ double mv[KK];
  __shared__ double dv[KK];

  double mtot;
  {
    double s = 0.0;
#pragma unroll
    for (int cc2 = 0; cc2 < CC; ++cc2) s += (double)gsum[cc2 * KK + t];
    mtot = s / (double)BB;
  }
  int nc = gcount[c];
  double safe = nc > 0 ? (double)nc : 1.0;
  double mt = (double)gsum[c * KK + t] / safe;
  double dt = mtot - mt;
  mv[t] = mt;
  dv[t] = dt;

  const double* Gc = G + (size_t)c * KK * KK;
  double tg = 0.0, qm = 0.0, qd = 0.0, tic = 0.0;
#pragma unroll 4
  for (int m = 0; m < KK; ++m) {
    double w = invS2[m * KK + t];   // coalesced, read once, used 4x
    tic += w * (double)cov[m * KK + t];
    tg += w * Gc[m * KK + t];
    qm += w * mv[m];                // broadcast LDS
    qd += w * dv[m];
  }
  qm *= mt;
  qd *= dt;
#pragma unroll
  for (int m = 32; m; m >>= 1) {
    tg += __shfl_down(tg, m);
    qm += __shfl_down(qm, m);
    qd += __shfl_down(qd, m);
    tic += __shfl_down(tic, m);
  }
  if (t == 0) {
    int best = 0;
    long long bv = -2;
    for (int cc2 = 0; cc2 < CC; ++cc2) {
      long long v = gcount[cc2] > 0 ? (long long)gfirst[cc2] : -1;
      if (v > bv) { bv = v; best = cc2; }   // strict > == argmax tie-break
    }
    double tr = tic + (tg - (double)nc * qm) / safe;
    double kl = 0.5 * (tr + qd - (double)KK + logdets[CC] - logdets[c]);
    double w = (nc > 0 && c != best) ? (double)nc : 0.0;
    atomicAdd(out, (float)(kl * w / (double)BB));
  }
}

extern "C" void kernel_launch(void* const* d_in, const int* in_sizes, int n_in,
                              void* d_out, int out_size, void* d_ws, size_t ws_size,
                              hipStream_t stream) {
  (void)in_sizes; (void)n_in; (void)out_size; (void)ws_size;
  const float* mu = (const float*)d_in[0];
  const int* labels = (const int*)d_in[1];
  const float* cov = (const float*)d_in[2];
  float* out = (float*)d_out;
  char* ws = (char*)d_ws;

  double* G = (double*)(ws + OFF_G);
  float* gsum = (float*)(ws + OFF_GSUM);
  int* gcount = (int*)(ws + OFF_GCOUNT);
  int* gfirst = (int*)(ws + OFF_GFIRST);
  double* invS2 = (double*)(ws + OFF_INV);
  double* logdets = (double*)(ws + OFF_LOG);

  // zero accumulators (G, gsum, gcount); gfirst -> 0x7f7f7f7f (acts as +inf for atomicMin)
  hipMemsetAsync(ws, 0, OFF_GFIRST, stream);
  hipMemsetAsync(ws + OFF_GFIRST, 0x7f, CC * sizeof(int), stream);

  gram_stats_kernel<<<dim3(32, CC), 256, 0, stream>>>(mu, labels, G, gsum, gcount, gfirst);
  factor_kernel<<<CC + 1, 64, 0, stream>>>(G, cov, gsum, gcount, invS2, logdets, out);
  combine_kernel<<<CC, 64, 0, stream>>>(G, invS2, logdets, cov, gcount, gfirst, gsum, out);
}

// Round 4
// 143.913 us; speedup vs baseline: 2.5927x; 1.2381x over previous
//
#include <hip/hip_runtime.h>

#define CC 8
#define KK 64
#define BB 8192
#define NCHUNK 16
#define ROWS_PER_CHUNK (BB / NCHUNK)   // 512

// ---------------- workspace layout (bytes) ----------------
#define OFF_G       0                         // double G[C][K][K]      = 262144
#define OFF_GSUM    262144                    // float  gsum[C][K]      =   2048
#define OFF_GCOUNT  264192                    // int    gcount[C]       =     32
#define OFF_GFIRST  264224                    // int    gfirst[C]       =     32  (init 0x7f)
#define OFF_INV     264256                    // double invS2[K][K]     =  32768
#define OFF_LOG     297024                    // double logdets[9]      =     72 (pad to 297096)
#define OFF_L       297096                    // double Lg[K][K] colmaj =  32768
#define OFF_LDI     329864                    // double Ldig[K]         =    512
#define OFF_X       330376                    // double Xg[K][K]        =  32768
#define OFF_GPART   363144                    // float Gpart[16][8][4096] = 2097152

// ---------------- pass 1: per-(chunk,class) partial Grams + fused stats (no f64 atomics) ----
__global__ __launch_bounds__(256) void gram_stats_kernel(
    const float* __restrict__ mu, const int* __restrict__ labels,
    float* __restrict__ Gpart, float* __restrict__ gsum,
    int* __restrict__ gcount, int* __restrict__ gfirst) {
  int c = blockIdx.y;
  int chunk = blockIdx.x;
  int tid = threadIdx.x;
  int tx = tid & 15, ty = tid >> 4;
  __shared__ float rows[16][KK];
  __shared__ int labs[16];
  double acc[4][4];
#pragma unroll
  for (int a = 0; a < 4; ++a)
#pragma unroll
    for (int b = 0; b < 4; ++b) acc[a][b] = 0.0;
  float rsum = 0.f;               // per-column class sum (tid<64)
  int cnt = 0, first = BB;        // per-lane stats (tid<16, own staged row)
  int base = chunk * ROWS_PER_CHUNK;

  // prefetch round 0
  float pf[4];
  int plab = 0;
#pragma unroll
  for (int i = 0; i < 4; ++i) pf[i] = mu[(size_t)base * KK + tid + i * 256];
  if (tid < 16) plab = labels[base + tid];

  for (int r0 = 0; r0 < ROWS_PER_CHUNK; r0 += 16) {
    __syncthreads();   // previous round's readers done
#pragma unroll
    for (int i = 0; i < 4; ++i) {
      int idx = tid + i * 256;
      rows[idx >> 6][idx & 63] = pf[i];
    }
    if (tid < 16) labs[tid] = plab;
    __syncthreads();
    // prefetch next round (overlaps compute below)
    if (r0 + 16 < ROWS_PER_CHUNK) {
#pragma unroll
      for (int i = 0; i < 4; ++i)
        pf[i] = mu[(size_t)(base + r0 + 16) * KK + tid + i * 256];
      if (tid < 16) plab = labels[base + r0 + 16 + tid];
    }
    // stats: lanes 0..15 own one staged row each
    if (tid < 16 && labs[tid] == c) { cnt++; first = min(first, base + r0 + tid); }
    if (tid < 64) {
#pragma unroll 4
      for (int r = 0; r < 16; ++r)
        if (labs[r] == c) rsum += rows[r][tid];
    }
    // gram accumulate (block-uniform skip)
    for (int r = 0; r < 16; ++r) {
      if (labs[r] != c) continue;
      const float* rw = rows[r];
      float ai[4], bj[4];
#pragma unroll
      for (int a = 0; a < 4; ++a) ai[a] = rw[ty * 4 + a];
#pragma unroll
      for (int b = 0; b < 4; ++b) bj[b] = rw[tx * 4 + b];
#pragma unroll
      for (int a = 0; a < 4; ++a)
#pragma unroll
        for (int b = 0; b < 4; ++b) acc[a][b] += (double)ai[a] * (double)bj[b];
    }
  }
  // non-atomic partial store (every element of the slice written)
  float* Gp = Gpart + ((size_t)chunk * CC + c) * KK * KK;
#pragma unroll
  for (int a = 0; a < 4; ++a)
#pragma unroll
    for (int b = 0; b < 4; ++b)
      Gp[(ty * 4 + a) * KK + tx * 4 + b] = (float)acc[a][b];
  // stats reduce + tiny atomics
  if (tid < 64) atomicAdd(&gsum[c * KK + tid], rsum);
  if (tid < 16) {
#pragma unroll
    for (int off = 8; off; off >>= 1) {
      cnt += __shfl_down(cnt, off);
      first = min(first, __shfl_down(first, off));
    }
    if (tid == 0 && cnt) {
      atomicAdd(&gcount[c], cnt);
      atomicMin(&gfirst[c], first);
    }
  }
}

// ---------------- pass 1b: reduce partials -> G (f64) ----------------
__global__ __launch_bounds__(256) void greduce_kernel(
    const float* __restrict__ Gpart, double* __restrict__ G) {
  int c = blockIdx.y;
  int e = blockIdx.x * 256 + threadIdx.x;   // 0..4095
  double s = 0.0;
#pragma unroll
  for (int p = 0; p < NCHUNK; ++p)
    s += (double)Gpart[((size_t)p * CC + c) * KK * KK + e];
  G[(size_t)c * KK * KK + e] = s;
}

// ---------------- pass 2: blocked Cholesky (panel=8), logdets; blk CC dumps L ----------------
__global__ __launch_bounds__(64) void factor_kernel(
    const double* __restrict__ G, const float* __restrict__ cov,
    const float* __restrict__ gsum, const int* __restrict__ gcount,
    double* __restrict__ logdets, double* __restrict__ Lg,
    double* __restrict__ Ldig, float* __restrict__ out) {
  int blk = blockIdx.x;
  int t = threadIdx.x;  // 0..63, one wave
  __shared__ double bufA[KK][KK + 1];
  __shared__ double bufB[KK][KK + 1];
  __shared__ double panelb[8][KK];
  __shared__ double mb[KK];

  bool isS2 = (blk == CC);
  if (isS2 && t == 0) out[0] = 0.f;   // zero output accumulator for combine

  double safe = 1.0, ncd = 0.0;
  if (!isS2) {
    int nc = gcount[blk];
    ncd = (double)nc;
    safe = nc > 0 ? ncd : 1.0;
    mb[t] = (double)gsum[blk * KK + t] / safe;
  } else {
    double s = 0.0;
#pragma unroll
    for (int c = 0; c < CC; ++c) s += (double)gsum[c * KK + t];
    mb[t] = s / (double)BB;
  }
  double mt = mb[t];

  if (!isS2) {
    const double* Gc = G + (size_t)blk * KK * KK;
    double inv_safe = 1.0 / safe;
#pragma unroll 8
    for (int j = 0; j < KK; ++j)
      bufA[t][j] = (double)cov[j * KK + t] + (Gc[j * KK + t] - ncd * mt * mb[j]) * inv_safe;
  } else {
    const double invB = 1.0 / (double)BB;
#pragma unroll 4
    for (int j = 0; j < KK; ++j) {
      double g = 0.0;
#pragma unroll
      for (int c = 0; c < CC; ++c) g += G[(size_t)c * KK * KK + j * KK + t];
      bufA[t][j] = (double)cov[j * KK + t] + g * invB - mt * mb[j];
    }
  }

  double (*cur)[KK + 1] = bufA;
  double (*nxt)[KK + 1] = bufB;
  double ldacc = 0.0;
  int bound = t | 7;   // row t never needs columns beyond its own panel
#pragma unroll 1
  for (int p = 0; p < 8; ++p) {
    int P0 = p * 8;
    double cc_[8];
#pragma unroll
    for (int m = 0; m < 8; ++m) cc_[m] = cur[t][P0 + m];
    double uu[8];
    double pd = 1.0;
#pragma unroll
    for (int m = 0; m < 8; ++m) {
      double akk = __shfl(cc_[m], P0 + m);   // pivot (uniform)
      pd *= akk;
      // fast reciprocal: v_rcp_f64 + 2 Newton steps (rel err ~2^-50)
      double inv;
      asm("v_rcp_f64 %0, %1" : "=v"(inv) : "v"(akk));
      inv = inv * fma(-akk, inv, 2.0);
      inv = inv * fma(-akk, inv, 2.0);
      uu[m] = cc_[m] * inv;
      panelb[m][t] = cc_[m];
      if (isS2) {
        double rsv = sqrt(akk) * inv;        // 1/sqrt(akk)
        Lg[(P0 + m) * KK + t] = cc_[m] * rsv;  // col-major, coalesced; upper junk never read
        if (t == 0) Ldig[P0 + m] = rsv;
      }
#pragma unroll
      for (int mm = m + 1; mm < 8; ++mm)
        cc_[mm] -= uu[m] * __shfl(cc_[m], P0 + mm);
    }
    ldacc += log(pd);
    // trailing update: read cur, write nxt; skip columns this row never needs
#pragma unroll 1
    for (int j = P0 + 8; j < KK; j += 8) {
      if (j <= bound) {
        double aj[8];
#pragma unroll
        for (int q = 0; q < 8; ++q) aj[q] = cur[t][j + q];
#pragma unroll
        for (int m = 0; m < 8; ++m)
#pragma unroll
          for (int q = 0; q < 8; ++q)
            aj[q] -= uu[m] * panelb[m][j + q];   // broadcast reads
#pragma unroll
        for (int q = 0; q < 8; ++q) nxt[t][j + q] = aj[q];
      }
    }
    { auto tmp = cur; cur = nxt; nxt = tmp; }
  }
  if (t == 0) logdets[blk] = ldacc;
}

// ---------------- pass 2b: X = L^{-1}, column per lane ----------------
__global__ __launch_bounds__(64) void solve_kernel(
    const double* __restrict__ Lg, const double* __restrict__ Ldig,
    double* __restrict__ Xg) {
  int t = threadIdx.x;
  __shared__ double Lt[KK][KK];       // Lt[j][i] = L[i][j]
  __shared__ double Xs[KK][KK];       // Xs[i][t] = X[i][column t]
  __shared__ double Ldi[KK];
#pragma unroll 8
  for (int j = 0; j < KK; ++j) Lt[j][t] = Lg[j * KK + t];  // coalesced
  Ldi[t] = Ldig[t];
  __syncthreads();

#pragma unroll 1
  for (int g = 0; g < 8; ++g) {
    int I0 = g * 8;
    double sv[8], ldl[8];
#pragma unroll
    for (int m = 0; m < 8; ++m) { sv[m] = 0.0; ldl[m] = Ldi[I0 + m]; }
#pragma unroll 4
    for (int j = 0; j < I0; ++j) {
      double xj = Xs[j][t];                       // lane-consecutive
#pragma unroll
      for (int m = 0; m < 8; ++m) sv[m] += Lt[j][I0 + m] * xj;  // broadcast
    }
#pragma unroll
    for (int m = 0; m < 8; ++m) {
      int i = I0 + m;
      double x = (((i == t) ? 1.0 : 0.0) - sv[m]) * ldl[m];
#pragma unroll
      for (int mm = m + 1; mm < 8; ++mm) sv[mm] += Lt[i][I0 + mm] * x;
      Xs[i][t] = x;                               // zeros for i<t fall out naturally
    }
  }
  __syncthreads();
#pragma unroll 8
  for (int i = 0; i < KK; ++i) Xg[i * KK + t] = Xs[i][t];  // coalesced
}

// ---------------- pass 2c: invS2 = X^T X, 8 blocks, round-robin rows ----------------
__global__ __launch_bounds__(64) void xtx_kernel(
    const double* __restrict__ Xg, double* __restrict__ invS2) {
  int b = blockIdx.x;   // 0..7
  int t = threadIdx.x;  // 0..63
  __shared__ double Xs[KK][KK];
#pragma unroll 8
  for (int k = 0; k < KK; ++k) Xs[k][t] = Xg[k * KK + t];
  __syncthreads();
#pragma unroll 1
  for (int rr = 0; rr < 8; ++rr) {
    int r = b + rr * 8;            // round-robin: balanced work across blocks
    double s = 0.0;
#pragma unroll 4
    for (int k = r; k < KK; ++k) s += Xs[k][r] * Xs[k][t];  // broadcast x consecutive
    invS2[r * KK + t] = s;
  }
}

// ---------------- pass 3: per-class KL + weighted atomic combine ----------------
// tr(inv*S1c) = tr(inv*cov) + (tr(inv*Gc) - nc * m^T inv m)/safe
__global__ __launch_bounds__(64) void combine_kernel(
    const double* __restrict__ G, const double* __restrict__ invS2,
    const double* __restrict__ logdets, const float* __restrict__ cov,
    const int* __restrict__ gcount, const int* __restrict__ gfirst,
    const float* __restrict__ gsum, float* __restrict__ out) {
  int c = blockIdx.x;   // 0..7
  int t = threadIdx.x;  // 0..63
  __shared__ double mv[KK];
  __shared__ double dv[KK];

  double mtot;
  {
    double s = 0.0;
#pragma unroll
    for (int cc2 = 0; cc2 < CC; ++cc2) s += (double)gsum[cc2 * KK + t];
    mtot = s / (double)BB;
  }
  int nc = gcount[c];
  double safe = nc > 0 ? (double)nc : 1.0;
  double mt = (double)gsum[c * KK + t] / safe;
  double dt = mtot - mt;
  mv[t] = mt;
  dv[t] = dt;

  const double* Gc = G + (size_t)c * KK * KK;
  double tg = 0.0, qm = 0.0, qd = 0.0, tic = 0.0;
#pragma unroll 4
  for (int m = 0; m < KK; ++m) {
    double w = invS2[m * KK + t];
    tic += w * (double)cov[m * KK + t];
    tg += w * Gc[m * KK + t];
    qm += w * mv[m];
    qd += w * dv[m];
  }
  qm *= mt;
  qd *= dt;
#pragma unroll
  for (int m = 32; m; m >>= 1) {
    tg += __shfl_down(tg, m);
    qm += __shfl_down(qm, m);
    qd += __shfl_down(qd, m);
    tic += __shfl_down(tic, m);
  }
  if (t == 0) {
    int best = 0;
    long long bv = -2;
    for (int cc2 = 0; cc2 < CC; ++cc2) {
      long long v = gcount[cc2] > 0 ? (long long)gfirst[cc2] : -1;
      if (v > bv) { bv = v; best = cc2; }
    }
    double tr = tic + (tg - (double)nc * qm) / safe;
    double kl = 0.5 * (tr + qd - (double)KK + logdets[CC] - logdets[c]);
    double w = (nc > 0 && c != best) ? (double)nc : 0.0;
    atomicAdd(out, (float)(kl * w / (double)BB));
  }
}

extern "C" void kernel_launch(void* const* d_in, const int* in_sizes, int n_in,
                              void* d_out, int out_size, void* d_ws, size_t ws_size,
                              hipStream_t stream) {
  (void)in_sizes; (void)n_in; (void)out_size; (void)ws_size;
  const float* mu = (const float*)d_in[0];
  const int* labels = (const int*)d_in[1];
  const float* cov = (const float*)d_in[2];
  float* out = (float*)d_out;
  char* ws = (char*)d_ws;

  double* G = (double*)(ws + OFF_G);
  float* gsum = (float*)(ws + OFF_GSUM);
  int* gcount = (int*)(ws + OFF_GCOUNT);
  int* gfirst = (int*)(ws + OFF_GFIRST);
  double* invS2 = (double*)(ws + OFF_INV);
  double* logdets = (double*)(ws + OFF_LOG);
  double* Lg = (double*)(ws + OFF_L);
  double* Ldig = (double*)(ws + OFF_LDI);
  double* Xg = (double*)(ws + OFF_X);
  float* Gpart = (float*)(ws + OFF_GPART);

  // zero gsum+gcount; gfirst -> 0x7f7f7f7f (+inf for atomicMin). G/Gpart fully overwritten.
  hipMemsetAsync(ws + OFF_GSUM, 0, OFF_GFIRST - OFF_GSUM, stream);
  hipMemsetAsync(ws + OFF_GFIRST, 0x7f, CC * sizeof(int), stream);

  gram_stats_kernel<<<dim3(NCHUNK, CC), 256, 0, stream>>>(mu, labels, Gpart, gsum, gcount, gfirst);
  greduce_kernel<<<dim3(16, CC), 256, 0, stream>>>(Gpart, G);
  factor_kernel<<<CC + 1, 64, 0, stream>>>(G, cov, gsum, gcount, logdets, Lg, Ldig, out);
  solve_kernel<<<1, 64, 0, stream>>>(Lg, Ldig, Xg);
  xtx_kernel<<<CC, 64, 0, stream>>>(Xg, invS2);
  combine_kernel<<<CC, 64, 0, stream>>>(G, invS2, logdets, cov, gcount, gfirst, gsum, out);
}

// Round 5
// 117.217 us; speedup vs baseline: 3.1832x; 1.2278x over previous
//
#include <hip/hip_runtime.h>

#define CC 8
#define KK 64
#define BB 8192
#define NCHUNK 16
#define ROWS_PER_CHUNK (BB / NCHUNK)   // 512

// ---------------- workspace layout (bytes) ----------------
#define OFF_G       0                         // double G[C][K][K]      = 262144
#define OFF_GSUM    262144                    // float  gsum[C][K]      =   2048
#define OFF_GCOUNT  264192                    // int    gcount[C]       =     32
#define OFF_GFIRST  264224                    // int    gfirst[C]       =     32  (init 0x7f)
#define OFF_INV     264256                    // double invS2[K][K]     =  32768
#define OFF_LOG     297024                    // double logdets[9]      =     72 (pad to 297096)
#define OFF_L       297096                    // double Lg[K][K] colmaj =  32768
#define OFF_LDI     329864                    // double Ldig[K]         =    512
#define OFF_X       330376                    // double Xg[K][K]        =  32768
#define OFF_GPART   363144                    // float Gpart[16][8][4096] = 2097152

// ---------------- pass 1: per-(chunk,class) partial Grams + fused stats ----------------
// 64-row staging groups (8 iters/block), float4 staging, ballot match-mask walk.
__global__ __launch_bounds__(256) void gram_stats_kernel(
    const float* __restrict__ mu, const int* __restrict__ labels,
    float* __restrict__ Gpart, float* __restrict__ gsum,
    int* __restrict__ gcount, int* __restrict__ gfirst) {
  int c = blockIdx.y;
  int chunk = blockIdx.x;
  int tid = threadIdx.x;
  int lane = tid & 63, w = tid >> 6;        // wave id 0..3
  int tx = tid & 15, ty = tid >> 4;
  __shared__ float rows[64][KK];            // 16 KB staged group
  __shared__ int labs[64];
  __shared__ float ssum[KK];
  double acc[4][4] = {{0.0}};
  float rsum = 0.f;
  int cnt = 0, first = BB;
  int base = chunk * ROWS_PER_CHUNK;
  const float4* mu4 = (const float4*)mu + (size_t)base * (KK / 4);

  if (tid < KK) ssum[tid] = 0.f;

  // prefetch group 0 (coalesced float4)
  float4 pf[4];
  int plab = 0;
#pragma unroll
  for (int i = 0; i < 4; ++i) pf[i] = mu4[tid + i * 256];
  if (tid < 64) plab = labels[base + tid];

#pragma unroll 1
  for (int g = 0; g < ROWS_PER_CHUNK / 64; ++g) {
    __syncthreads();
    float4* rows4 = (float4*)&rows[0][0];
#pragma unroll
    for (int i = 0; i < 4; ++i) rows4[tid + i * 256] = pf[i];
    if (tid < 64) labs[tid] = plab;
    __syncthreads();
    // prefetch next group (latency hides under this group's compute)
    if (g + 1 < ROWS_PER_CHUNK / 64) {
#pragma unroll
      for (int i = 0; i < 4; ++i) pf[i] = mu4[(g + 1) * 1024 + tid + i * 256];
      if (tid < 64) plab = labels[base + (g + 1) * 64 + tid];
    }
    // stats: wave w owns staged rows w*16 .. w*16+15
#pragma unroll 4
    for (int r = 0; r < 16; ++r) {
      int rr = w * 16 + r;
      if (labs[rr] == c) rsum += rows[rr][lane];   // uniform branch, lane-consec read
    }
    if (lane < 16 && labs[w * 16 + lane] == c) {
      cnt++;
      first = min(first, base + g * 64 + w * 16 + lane);
    }
    // gram: uniform 64-bit match mask, walk set bits only (~8 avg)
    unsigned long long m = __ballot(labs[lane] == c);
    while (m) {
      int r = __builtin_ctzll(m);
      m &= m - 1;
      const float4* rw4 = (const float4*)rows[r];
      float4 a4 = rw4[ty], b4 = rw4[tx];           // 2x ds_read_b128
      const float* ai = (const float*)&a4;
      const float* bj = (const float*)&b4;
#pragma unroll
      for (int a = 0; a < 4; ++a)
#pragma unroll
        for (int b = 0; b < 4; ++b) acc[a][b] += (double)ai[a] * (double)bj[b];
    }
  }
  // non-atomic partial store
  float* Gp = Gpart + ((size_t)chunk * CC + c) * KK * KK;
#pragma unroll
  for (int a = 0; a < 4; ++a)
#pragma unroll
    for (int b = 0; b < 4; ++b)
      Gp[(ty * 4 + a) * KK + tx * 4 + b] = (float)acc[a][b];
  // stats reduce: LDS across waves, then one global atomic per column
  atomicAdd(&ssum[lane], rsum);
  __syncthreads();
  if (tid < KK) {
    float v = ssum[tid];
    if (v != 0.f) atomicAdd(&gsum[c * KK + tid], v);
  }
  if (lane < 16) {
#pragma unroll
    for (int off = 8; off; off >>= 1) {
      cnt += __shfl_down(cnt, off);
      first = min(first, __shfl_down(first, off));
    }
    if (lane == 0 && cnt) {
      atomicAdd(&gcount[c], cnt);
      atomicMin(&gfirst[c], first);
    }
  }
}

// ---------------- pass 1b: reduce partials -> G (f64) ----------------
__global__ __launch_bounds__(256) void greduce_kernel(
    const float* __restrict__ Gpart, double* __restrict__ G) {
  int c = blockIdx.y;
  int e = blockIdx.x * 256 + threadIdx.x;   // 0..4095
  double s = 0.0;
#pragma unroll
  for (int p = 0; p < NCHUNK; ++p)
    s += (double)Gpart[((size_t)p * CC + c) * KK * KK + e];
  G[(size_t)c * KK * KK + e] = s;
}

// ---------------- pass 2: blocked Cholesky (panel=8), logdets; blk CC dumps L ----------------
__global__ __launch_bounds__(64) void factor_kernel(
    const double* __restrict__ G, const float* __restrict__ cov,
    const float* __restrict__ gsum, const int* __restrict__ gcount,
    double* __restrict__ logdets, double* __restrict__ Lg,
    double* __restrict__ Ldig, float* __restrict__ out) {
  int blk = blockIdx.x;
  int t = threadIdx.x;  // 0..63, one wave
  __shared__ double bufA[KK][KK + 1];
  __shared__ double bufB[KK][KK + 1];
  __shared__ double panelb[8][KK];
  __shared__ double mb[KK];

  bool isS2 = (blk == CC);
  if (isS2 && t == 0) out[0] = 0.f;   // zero output accumulator for combine

  double safe = 1.0, ncd = 0.0;
  if (!isS2) {
    int nc = gcount[blk];
    ncd = (double)nc;
    safe = nc > 0 ? ncd : 1.0;
    mb[t] = (double)gsum[blk * KK + t] / safe;
  } else {
    double s = 0.0;
#pragma unroll
    for (int c = 0; c < CC; ++c) s += (double)gsum[c * KK + t];
    mb[t] = s / (double)BB;
  }
  double mt = mb[t];

  if (!isS2) {
    const double* Gc = G + (size_t)blk * KK * KK;
    double inv_safe = 1.0 / safe;
#pragma unroll 8
    for (int j = 0; j < KK; ++j)
      bufA[t][j] = (double)cov[j * KK + t] + (Gc[j * KK + t] - ncd * mt * mb[j]) * inv_safe;
  } else {
    const double invB = 1.0 / (double)BB;
#pragma unroll 4
    for (int j = 0; j < KK; ++j) {
      double g = 0.0;
#pragma unroll
      for (int c = 0; c < CC; ++c) g += G[(size_t)c * KK * KK + j * KK + t];
      bufA[t][j] = (double)cov[j * KK + t] + g * invB - mt * mb[j];
    }
  }

  double (*cur)[KK + 1] = bufA;
  double (*nxt)[KK + 1] = bufB;
  double ldacc = 0.0;
  int bound = t | 7;   // row t never needs columns beyond its own panel
#pragma unroll 1
  for (int p = 0; p < 8; ++p) {
    int P0 = p * 8;
    double cc_[8];
#pragma unroll
    for (int m = 0; m < 8; ++m) cc_[m] = cur[t][P0 + m];
    double uu[8];
    double pd = 1.0;
#pragma unroll
    for (int m = 0; m < 8; ++m) {
      double akk = __shfl(cc_[m], P0 + m);   // pivot (uniform)
      pd *= akk;
      double inv;
      asm("v_rcp_f64 %0, %1" : "=v"(inv) : "v"(akk));
      inv = inv * fma(-akk, inv, 2.0);
      inv = inv * fma(-akk, inv, 2.0);
      uu[m] = cc_[m] * inv;
      panelb[m][t] = cc_[m];
      if (isS2) {
        double rsv = sqrt(akk) * inv;        // 1/sqrt(akk)
        Lg[(P0 + m) * KK + t] = cc_[m] * rsv;  // col-major, coalesced
        if (t == 0) Ldig[P0 + m] = rsv;
      }
#pragma unroll
      for (int mm = m + 1; mm < 8; ++mm)
        cc_[mm] -= uu[m] * __shfl(cc_[m], P0 + mm);
    }
    ldacc += log(pd);
#pragma unroll 1
    for (int j = P0 + 8; j < KK; j += 8) {
      if (j <= bound) {
        double aj[8];
#pragma unroll
        for (int q = 0; q < 8; ++q) aj[q] = cur[t][j + q];
#pragma unroll
        for (int m = 0; m < 8; ++m)
#pragma unroll
          for (int q = 0; q < 8; ++q)
            aj[q] -= uu[m] * panelb[m][j + q];   // broadcast reads
#pragma unroll
        for (int q = 0; q < 8; ++q) nxt[t][j + q] = aj[q];
      }
    }
    { auto tmp = cur; cur = nxt; nxt = tmp; }
  }
  if (t == 0) logdets[blk] = ldacc;
}

// ---------------- pass 2b: X = L^{-1}, column per lane ----------------
__global__ __launch_bounds__(64) void solve_kernel(
    const double* __restrict__ Lg, const double* __restrict__ Ldig,
    double* __restrict__ Xg) {
  int t = threadIdx.x;
  __shared__ double Lt[KK][KK];       // Lt[j][i] = L[i][j]
  __shared__ double Xs[KK][KK];       // Xs[i][t] = X[i][column t]
  __shared__ double Ldi[KK];
#pragma unroll 8
  for (int j = 0; j < KK; ++j) Lt[j][t] = Lg[j * KK + t];  // coalesced
  Ldi[t] = Ldig[t];
  __syncthreads();

#pragma unroll 1
  for (int g = 0; g < 8; ++g) {
    int I0 = g * 8;
    double sv[8], ldl[8];
#pragma unroll
    for (int m = 0; m < 8; ++m) { sv[m] = 0.0; ldl[m] = Ldi[I0 + m]; }
#pragma unroll 4
    for (int j = 0; j < I0; ++j) {
      double xj = Xs[j][t];                       // lane-consecutive
#pragma unroll
      for (int m = 0; m < 8; ++m) sv[m] += Lt[j][I0 + m] * xj;  // broadcast
    }
#pragma unroll
    for (int m = 0; m < 8; ++m) {
      int i = I0 + m;
      double x = (((i == t) ? 1.0 : 0.0) - sv[m]) * ldl[m];
#pragma unroll
      for (int mm = m + 1; mm < 8; ++mm) sv[mm] += Lt[i][I0 + mm] * x;
      Xs[i][t] = x;
    }
  }
  __syncthreads();
#pragma unroll 8
  for (int i = 0; i < KK; ++i) Xg[i * KK + t] = Xs[i][t];  // coalesced
}

// ---------------- pass 2c: invS2 = X^T X, 8 blocks, round-robin rows ----------------
__global__ __launch_bounds__(64) void xtx_kernel(
    const double* __restrict__ Xg, double* __restrict__ invS2) {
  int b = blockIdx.x;   // 0..7
  int t = threadIdx.x;  // 0..63
  __shared__ double Xs[KK][KK];
#pragma unroll 8
  for (int k = 0; k < KK; ++k) Xs[k][t] = Xg[k * KK + t];
  __syncthreads();
#pragma unroll 1
  for (int rr = 0; rr < 8; ++rr) {
    int r = b + rr * 8;
    double s = 0.0;
#pragma unroll 4
    for (int k = r; k < KK; ++k) s += Xs[k][r] * Xs[k][t];
    invS2[r * KK + t] = s;
  }
}

// ---------------- pass 3: per-class KL + weighted atomic combine ----------------
__global__ __launch_bounds__(64) void combine_kernel(
    const double* __restrict__ G, const double* __restrict__ invS2,
    const double* __restrict__ logdets, const float* __restrict__ cov,
    const int* __restrict__ gcount, const int* __restrict__ gfirst,
    const float* __restrict__ gsum, float* __restrict__ out) {
  int c = blockIdx.x;   // 0..7
  int t = threadIdx.x;  // 0..63
  __shared__ double mv[KK];
  __shared__ double dv[KK];

  double mtot;
  {
    double s = 0.0;
#pragma unroll
    for (int cc2 = 0; cc2 < CC; ++cc2) s += (double)gsum[cc2 * KK + t];
    mtot = s / (double)BB;
  }
  int nc = gcount[c];
  double safe = nc > 0 ? (double)nc : 1.0;
  double mt = (double)gsum[c * KK + t] / safe;
  double dt = mtot - mt;
  mv[t] = mt;
  dv[t] = dt;

  const double* Gc = G + (size_t)c * KK * KK;
  double tg = 0.0, qm = 0.0, qd = 0.0, tic = 0.0;
#pragma unroll 4
  for (int m = 0; m < KK; ++m) {
    double w = invS2[m * KK + t];
    tic += w * (double)cov[m * KK + t];
    tg += w * Gc[m * KK + t];
    qm += w * mv[m];
    qd += w * dv[m];
  }
  qm *= mt;
  qd *= dt;
#pragma unroll
  for (int m = 32; m; m >>= 1) {
    tg += __shfl_down(tg, m);
    qm += __shfl_down(qm, m);
    qd += __shfl_down(qd, m);
    tic += __shfl_down(tic, m);
  }
  if (t == 0) {
    int best = 0;
    long long bv = -2;
    for (int cc2 = 0; cc2 < CC; ++cc2) {
      long long v = gcount[cc2] > 0 ? (long long)gfirst[cc2] : -1;
      if (v > bv) { bv = v; best = cc2; }
    }
    double tr = tic + (tg - (double)nc * qm) / safe;
    double kl = 0.5 * (tr + qd - (double)KK + logdets[CC] - logdets[c]);
    double w = (nc > 0 && c != best) ? (double)nc : 0.0;
    atomicAdd(out, (float)(kl * w / (double)BB));
  }
}

extern "C" void kernel_launch(void* const* d_in, const int* in_sizes, int n_in,
                              void* d_out, int out_size, void* d_ws, size_t ws_size,
                              hipStream_t stream) {
  (void)in_sizes; (void)n_in; (void)out_size; (void)ws_size;
  const float* mu = (const float*)d_in[0];
  const int* labels = (const int*)d_in[1];
  const float* cov = (const float*)d_in[2];
  float* out = (float*)d_out;
  char* ws = (char*)d_ws;

  double* G = (double*)(ws + OFF_G);
  float* gsum = (float*)(ws + OFF_GSUM);
  int* gcount = (int*)(ws + OFF_GCOUNT);
  int* gfirst = (int*)(ws + OFF_GFIRST);
  double* invS2 = (double*)(ws + OFF_INV);
  double* logdets = (double*)(ws + OFF_LOG);
  double* Lg = (double*)(ws + OFF_L);
  double* Ldig = (double*)(ws + OFF_LDI);
  double* Xg = (double*)(ws + OFF_X);
  float* Gpart = (float*)(ws + OFF_GPART);

  // zero gsum+gcount; gfirst -> 0x7f7f7f7f (+inf for atomicMin). G/Gpart fully overwritten.
  hipMemsetAsync(ws + OFF_GSUM, 0, OFF_GFIRST - OFF_GSUM, stream);
  hipMemsetAsync(ws + OFF_GFIRST, 0x7f, CC * sizeof(int), stream);

  gram_stats_kernel<<<dim3(NCHUNK, CC), 256, 0, stream>>>(mu, labels, Gpart, gsum, gcount, gfirst);
  greduce_kernel<<<dim3(16, CC), 256, 0, stream>>>(Gpart, G);
  factor_kernel<<<CC + 1, 64, 0, stream>>>(G, cov, gsum, gcount, logdets, Lg, Ldig, out);
  solve_kernel<<<1, 64, 0, stream>>>(Lg, Ldig, Xg);
  xtx_kernel<<<CC, 64, 0, stream>>>(Xg, invS2);
  combine_kernel<<<CC, 64, 0, stream>>>(G, invS2, logdets, cov, gcount, gfirst, gsum, out);
}

// Round 6
// 107.887 us; speedup vs baseline: 3.4585x; 1.0865x over previous
//
#include <hip/hip_runtime.h>

#define CC 8
#define KK 64
#define BB 8192
#define NCHUNK 16
#define ROWS_PER_CHUNK (BB / NCHUNK)   // 512

// ---------------- workspace layout (bytes) ----------------
#define OFF_G       0                         // double G[9][K][K] (class 8 = total) = 294912
#define OFF_GSUM    294912                    // float  gsum[C][K]      =   2048
#define OFF_GCOUNT  296960                    // int    gcount[C]       =     32
#define OFF_GFIRST  296992                    // int    gfirst[C]       =     32  (init 0x7f)
#define OFF_INV     297024                    // double invS2[K][K]     =  32768
#define OFF_LOG     329792                    // double logdets[9]      =     72
#define OFF_GPART   329864                    // float Gpart[16][8][4096] = 2097152

__device__ __forceinline__ double readlane_f64(double v, int lane) {
  union { double d; int i[2]; } u, r;
  u.d = v;
  r.i[0] = __builtin_amdgcn_readlane(u.i[0], lane);
  r.i[1] = __builtin_amdgcn_readlane(u.i[1], lane);
  return r.d;
}

// ---------------- pass 1: per-(chunk,class) partial Grams + fused stats ----------------
__global__ __launch_bounds__(256) void gram_stats_kernel(
    const float* __restrict__ mu, const int* __restrict__ labels,
    float* __restrict__ Gpart, float* __restrict__ gsum,
    int* __restrict__ gcount, int* __restrict__ gfirst) {
  int c = blockIdx.y;
  int chunk = blockIdx.x;
  int tid = threadIdx.x;
  int lane = tid & 63, w = tid >> 6;
  int tx = tid & 15, ty = tid >> 4;
  __shared__ float rows[64][KK];
  __shared__ int labs[64];
  __shared__ float ssum[KK];
  double acc[4][4] = {{0.0}};
  float rsum = 0.f;
  int cnt = 0, first = BB;
  int base = chunk * ROWS_PER_CHUNK;
  const float4* mu4 = (const float4*)mu + (size_t)base * (KK / 4);

  if (tid < KK) ssum[tid] = 0.f;

  float4 pf[4];
  int plab = 0;
#pragma unroll
  for (int i = 0; i < 4; ++i) pf[i] = mu4[tid + i * 256];
  if (tid < 64) plab = labels[base + tid];

#pragma unroll 1
  for (int g = 0; g < ROWS_PER_CHUNK / 64; ++g) {
    __syncthreads();
    float4* rows4 = (float4*)&rows[0][0];
#pragma unroll
    for (int i = 0; i < 4; ++i) rows4[tid + i * 256] = pf[i];
    if (tid < 64) labs[tid] = plab;
    __syncthreads();
    if (g + 1 < ROWS_PER_CHUNK / 64) {
#pragma unroll
      for (int i = 0; i < 4; ++i) pf[i] = mu4[(g + 1) * 1024 + tid + i * 256];
      if (tid < 64) plab = labels[base + (g + 1) * 64 + tid];
    }
#pragma unroll 4
    for (int r = 0; r < 16; ++r) {
      int rr = w * 16 + r;
      if (labs[rr] == c) rsum += rows[rr][lane];
    }
    if (lane < 16 && labs[w * 16 + lane] == c) {
      cnt++;
      first = min(first, base + g * 64 + w * 16 + lane);
    }
    unsigned long long m = __ballot(labs[lane] == c);
    while (m) {
      int r = __builtin_ctzll(m);
      m &= m - 1;
      const float4* rw4 = (const float4*)rows[r];
      float4 a4 = rw4[ty], b4 = rw4[tx];
      const float* ai = (const float*)&a4;
      const float* bj = (const float*)&b4;
#pragma unroll
      for (int a = 0; a < 4; ++a)
#pragma unroll
        for (int b = 0; b < 4; ++b) acc[a][b] += (double)ai[a] * (double)bj[b];
    }
  }
  float* Gp = Gpart + ((size_t)chunk * CC + c) * KK * KK;
#pragma unroll
  for (int a = 0; a < 4; ++a)
#pragma unroll
    for (int b = 0; b < 4; ++b)
      Gp[(ty * 4 + a) * KK + tx * 4 + b] = (float)acc[a][b];
  atomicAdd(&ssum[lane], rsum);
  __syncthreads();
  if (tid < KK) {
    float v = ssum[tid];
    if (v != 0.f) atomicAdd(&gsum[c * KK + tid], v);
  }
  if (lane < 16) {
#pragma unroll
    for (int off = 8; off; off >>= 1) {
      cnt += __shfl_down(cnt, off);
      first = min(first, __shfl_down(first, off));
    }
    if (lane == 0 && cnt) {
      atomicAdd(&gcount[c], cnt);
      atomicMin(&gfirst[c], first);
    }
  }
}

// ---------------- pass 1b: reduce partials -> G (f64); class 8 = total ----------------
__global__ __launch_bounds__(256) void greduce_kernel(
    const float* __restrict__ Gpart, double* __restrict__ G) {
  int c = blockIdx.y;                        // 0..8
  int e = blockIdx.x * 256 + threadIdx.x;    // 0..4095
  double s = 0.0;
  if (c < CC) {
#pragma unroll
    for (int p = 0; p < NCHUNK; ++p)
      s += (double)Gpart[((size_t)p * CC + c) * KK * KK + e];
  } else {
#pragma unroll 4
    for (int p = 0; p < NCHUNK; ++p)
#pragma unroll
      for (int c2 = 0; c2 < CC; ++c2)
        s += (double)Gpart[((size_t)p * CC + c2) * KK * KK + e];
  }
  G[(size_t)c * KK * KK + e] = s;
}

// ---------------- pass 2: 4-wave blocked Cholesky + fused solve/XtX for block 8 ----------
// 9 blocks x 256 threads. Lane = row. Panel factorization: redundant per wave, registers +
// readlane (literal lanes). Build & trailing update split across the 4 waves.
__global__ __launch_bounds__(256) void factor_kernel(
    const double* __restrict__ G, const float* __restrict__ cov,
    const float* __restrict__ gsum, const int* __restrict__ gcount,
    double* __restrict__ logdets, double* __restrict__ invS2,
    float* __restrict__ out) {
  int blk = blockIdx.x;
  int tid = threadIdx.x;
  int t = tid & 63;     // row
  int w = tid >> 6;     // wave 0..3
  __shared__ double bufA[KK][KK + 1];
  __shared__ double bufB[KK][KK + 1];
  __shared__ double panelb[8][KK];
  __shared__ double Lb[KK][KK + 1];   // normalized L (block 8 only)
  __shared__ double Ldi[KK];          // 1/L[i][i]   (block 8 only)
  __shared__ double mb[KK];

  bool isS2 = (blk == CC);
  if (isS2 && tid == 0) out[0] = 0.f;   // zero output accumulator for combine

  // ---- mean (redundant per wave; wave 0 publishes) ----
  double safe, ncd, mt;
  if (!isS2) {
    int nc = gcount[blk];
    ncd = (double)nc;
    safe = nc > 0 ? ncd : 1.0;
    mt = (double)gsum[blk * KK + t] / safe;
  } else {
    ncd = (double)BB;
    safe = (double)BB;
    double s = 0.0;
#pragma unroll
    for (int c = 0; c < CC; ++c) s += (double)gsum[c * KK + t];
    mt = s / safe;
  }
  if (w == 0) mb[t] = mt;
  __syncthreads();

  // ---- build Sigma: wave w fills columns [16w, 16w+16)  (G[8] = total Gram) ----
  {
    const double* Gc = G + (size_t)blk * KK * KK;
    double inv_safe = 1.0 / safe;
    int j0 = w * 16;
#pragma unroll 4
    for (int jj = 0; jj < 16; ++jj) {
      int j = j0 + jj;
      bufA[t][j] = (double)cov[j * KK + t] + (Gc[j * KK + t] - ncd * mt * mb[j]) * inv_safe;
    }
  }
  __syncthreads();

  // ---- blocked Cholesky: panel redundant per wave, trailing split by j-block ----
  double (*cur)[KK + 1] = bufA;
  double (*nxt)[KK + 1] = bufB;
  double ldacc = 0.0;
  int bound = t | 7;
#pragma unroll
  for (int p = 0; p < 8; ++p) {
    const int P0 = p * 8;
    double cc_[8];
#pragma unroll
    for (int m = 0; m < 8; ++m) cc_[m] = cur[t][P0 + m];
    double uu[8];
    double pd = 1.0;
#pragma unroll
    for (int m = 0; m < 8; ++m) {
      double akk = readlane_f64(cc_[m], P0 + m);   // literal lane -> v_readlane
      pd *= akk;
      double inv;
      asm("v_rcp_f64 %0, %1" : "=v"(inv) : "v"(akk));
      inv = inv * fma(-akk, inv, 2.0);
      inv = inv * fma(-akk, inv, 2.0);
      uu[m] = cc_[m] * inv;
      if (w == 0) {
        panelb[m][t] = cc_[m];
        if (isS2) {
          double rsv = sqrt(akk) * inv;            // 1/sqrt(akk)
          Lb[t][P0 + m] = cc_[m] * rsv;
          if (t == 0) Ldi[P0 + m] = rsv;
        }
      }
#pragma unroll
      for (int mm = m + 1; mm < 8; ++mm)
        cc_[mm] -= uu[m] * readlane_f64(cc_[m], P0 + mm);
    }
    ldacc += log(pd);
    __syncthreads();                    // panelb visible
#pragma unroll 1
    for (int jb = p + 1 + w; jb < 8; jb += 4) {   // wave-split trailing update
      int j = jb * 8;
      if (j <= bound) {
        double aj[8];
#pragma unroll
        for (int q = 0; q < 8; ++q) aj[q] = cur[t][j + q];
#pragma unroll
        for (int m = 0; m < 8; ++m)
#pragma unroll
          for (int q = 0; q < 8; ++q)
            aj[q] -= uu[m] * panelb[m][j + q];     // broadcast reads
#pragma unroll
        for (int q = 0; q < 8; ++q) nxt[t][j + q] = aj[q];
      }
    }
    __syncthreads();                    // nxt complete
    { auto tmp = cur; cur = nxt; nxt = tmp; }
  }
  if (tid == 0) logdets[blk] = ldacc;

  // ---- block 8: X = L^{-1} (wave 0), then invS2 = X^T X (4 waves) ----
  if (isS2) {
    double (*Xs)[KK] = (double (*)[KK])(&bufA[0][0]);   // reuse bufA
    if (w == 0) {
#pragma unroll 1
      for (int g = 0; g < 8; ++g) {
        int I0 = g * 8;
        double sv[8];
#pragma unroll
        for (int m = 0; m < 8; ++m) sv[m] = 0.0;
#pragma unroll 2
        for (int j = 0; j < I0; ++j) {
          double xj = Xs[j][t];                   // own column, lane-consecutive
#pragma unroll
          for (int m = 0; m < 8; ++m) sv[m] += Lb[I0 + m][j] * xj;  // broadcast
        }
#pragma unroll
        for (int m = 0; m < 8; ++m) {
          int i = I0 + m;
          double x = (((i == t) ? 1.0 : 0.0) - sv[m]) * Ldi[i];
#pragma unroll
          for (int mm = m + 1; mm < 8; ++mm) sv[mm] += Lb[I0 + mm][i] * x;
          Xs[i][t] = x;                           // zeros for i<t fall out naturally
        }
      }
    }
    __syncthreads();
    // invS2[r][c] = sum_{k>=r} X[k][r] X[k][c]; rows round-robin across waves
#pragma unroll 1
    for (int rr = 0; rr < 16; ++rr) {
      int r = w + rr * 4;
      double s = 0.0;
#pragma unroll 2
      for (int k = r; k < KK; ++k) s += Xs[k][r] * Xs[k][t];
      invS2[r * KK + t] = s;           // coalesced
    }
  }
}

// ---------------- pass 3: per-class KL + weighted atomic combine ----------------
__global__ __launch_bounds__(64) void combine_kernel(
    const double* __restrict__ G, const double* __restrict__ invS2,
    const double* __restrict__ logdets, const float* __restrict__ cov,
    const int* __restrict__ gcount, const int* __restrict__ gfirst,
    const float* __restrict__ gsum, float* __restrict__ out) {
  int c = blockIdx.x;
  int t = threadIdx.x;
  __shared__ double mv[KK];
  __shared__ double dv[KK];

  double mtot;
  {
    double s = 0.0;
#pragma unroll
    for (int cc2 = 0; cc2 < CC; ++cc2) s += (double)gsum[cc2 * KK + t];
    mtot = s / (double)BB;
  }
  int nc = gcount[c];
  double safe = nc > 0 ? (double)nc : 1.0;
  double mt = (double)gsum[c * KK + t] / safe;
  double dt = mtot - mt;
  mv[t] = mt;
  dv[t] = dt;

  const double* Gc = G + (size_t)c * KK * KK;
  double tg = 0.0, qm = 0.0, qd = 0.0, tic = 0.0;
#pragma unroll 4
  for (int m = 0; m < KK; ++m) {
    double w = invS2[m * KK + t];
    tic += w * (double)cov[m * KK + t];
    tg += w * Gc[m * KK + t];
    qm += w * mv[m];
    qd += w * dv[m];
  }
  qm *= mt;
  qd *= dt;
#pragma unroll
  for (int m = 32; m; m >>= 1) {
    tg += __shfl_down(tg, m);
    qm += __shfl_down(qm, m);
    qd += __shfl_down(qd, m);
    tic += __shfl_down(tic, m);
  }
  if (t == 0) {
    int best = 0;
    long long bv = -2;
    for (int cc2 = 0; cc2 < CC; ++cc2) {
      long long v = gcount[cc2] > 0 ? (long long)gfirst[cc2] : -1;
      if (v > bv) { bv = v; best = cc2; }
    }
    double tr = tic + (tg - (double)nc * qm) / safe;
    double kl = 0.5 * (tr + qd - (double)KK + logdets[CC] - logdets[c]);
    double wgt = (nc > 0 && c != best) ? (double)nc : 0.0;
    atomicAdd(out, (float)(kl * wgt / (double)BB));
  }
}

extern "C" void kernel_launch(void* const* d_in, const int* in_sizes, int n_in,
                              void* d_out, int out_size, void* d_ws, size_t ws_size,
                              hipStream_t stream) {
  (void)in_sizes; (void)n_in; (void)out_size; (void)ws_size;
  const float* mu = (const float*)d_in[0];
  const int* labels = (const int*)d_in[1];
  const float* cov = (const float*)d_in[2];
  float* out = (float*)d_out;
  char* ws = (char*)d_ws;

  double* G = (double*)(ws + OFF_G);
  float* gsum = (float*)(ws + OFF_GSUM);
  int* gcount = (int*)(ws + OFF_GCOUNT);
  int* gfirst = (int*)(ws + OFF_GFIRST);
  double* invS2 = (double*)(ws + OFF_INV);
  double* logdets = (double*)(ws + OFF_LOG);
  float* Gpart = (float*)(ws + OFF_GPART);

  // zero gsum+gcount; gfirst -> 0x7f7f7f7f (+inf for atomicMin). G/Gpart fully overwritten.
  hipMemsetAsync(ws + OFF_GSUM, 0, OFF_GFIRST - OFF_GSUM, stream);
  hipMemsetAsync(ws + OFF_GFIRST, 0x7f, CC * sizeof(int), stream);

  gram_stats_kernel<<<dim3(NCHUNK, CC), 256, 0, stream>>>(mu, labels, Gpart, gsum, gcount, gfirst);
  greduce_kernel<<<dim3(16, CC + 1), 256, 0, stream>>>(Gpart, G);
  factor_kernel<<<CC + 1, 256, 0, stream>>>(G, cov, gsum, gcount, logdets, invS2, out);
  combine_kernel<<<CC, 64, 0, stream>>>(G, invS2, logdets, cov, gcount, gfirst, gsum, out);
}